// Round 2
// baseline (138.222 us; speedup 1.0000x reference)
//
#include <hip/hip_runtime.h>
#include <math.h>

#define FLT_BIG 3.0e38f

// Kernel A: per-ray min squared distance to all M points.
// Block 256 = 64 rays x 4 M-chunks. Grid (N/64, B).
// LDS: M float4 (x, y, z, 0.5*|q|^2) = 64KB -> 2 blocks/CU.
// Inner loop: e = 0.5|q|^2 - p.q  (min-equivalent to 0.5*dist^2 - 0.5|p|^2).
__global__ __launch_bounds__(256, 2) void chamfer_min_kernel(
    const float* __restrict__ cparam,   // B x 25
    const float* __restrict__ depth,    // B x N
    const float* __restrict__ pc,       // B x M x 3
    float* __restrict__ d0,             // B x N
    int N, int M, int R)
{
    const int b   = blockIdx.y;
    const int tid = threadIdx.x;

    extern __shared__ float4 s4[];      // M entries

    // Stage point cloud: (x,y,z, 0.5*(x^2+y^2+z^2))
    const float* pcb = pc + (size_t)b * M * 3;
    for (int idx = tid; idx < M; idx += 256) {
        float x = pcb[idx * 3 + 0];
        float y = pcb[idx * 3 + 1];
        float z = pcb[idx * 3 + 2];
        s4[idx] = make_float4(x, y, z, 0.5f * (x * x + y * y + z * z));
    }
    __syncthreads();

    // Camera params (wave-uniform scalar loads).
    const float* cb = cparam + (size_t)b * 25;
    const float fx = cb[16], sk = cb[17], cx = cb[18];
    const float fy = cb[20], cy = cb[21];

    const int chunk = tid & 3;          // which quarter of M (interleaved mod 4)
    const int rloc  = tid >> 2;         // ray within block: 0..63
    const int n     = blockIdx.x * 64 + rloc;

    const int i = n / R;
    const int j = n - i * R;
    const float x_cam = (j + 0.5f) / (float)R;
    const float y_cam = (i + 0.5f) / (float)R;

    const float x_lift = (x_cam - cx + cy * sk / fy - sk * y_cam / fy) / fx;
    const float y_lift = (y_cam - cy) / fy;

    // dir = R3x3 * [x_lift, y_lift, 1]; translation cancels in (world - origin).
    const float dxw = cb[0] * x_lift + cb[1] * y_lift + cb[2];
    const float dyw = cb[4] * x_lift + cb[5] * y_lift + cb[6];
    const float dzw = cb[8] * x_lift + cb[9] * y_lift + cb[10];
    const float inv = 1.0f / sqrtf(dxw * dxw + dyw * dyw + dzw * dzw);

    const float dep = depth[(size_t)b * N + n];
    const float px = cb[3]  + dep * dxw * inv;
    const float py = cb[7]  + dep * dyw * inv;
    const float pz = cb[11] + dep * dzw * inv;

    // Points idx ≡ chunk (mod 4); per iter: ds_read_b128 + 3 FMA + 1 min.
    const int Mq = M >> 2;
    const float4* p = s4 + chunk;
    float e0 = FLT_BIG, e1 = FLT_BIG, e2 = FLT_BIG, e3 = FLT_BIG;
    for (int m = 0; m < Mq; m += 4) {
        float4 q0 = p[(m + 0) << 2];
        float4 q1 = p[(m + 1) << 2];
        float4 q2 = p[(m + 2) << 2];
        float4 q3 = p[(m + 3) << 2];
        e0 = fminf(e0, fmaf(-px, q0.x, fmaf(-py, q0.y, fmaf(-pz, q0.z, q0.w))));
        e1 = fminf(e1, fmaf(-px, q1.x, fmaf(-py, q1.y, fmaf(-pz, q1.z, q1.w))));
        e2 = fminf(e2, fmaf(-px, q2.x, fmaf(-py, q2.y, fmaf(-pz, q2.z, q2.w))));
        e3 = fminf(e3, fmaf(-px, q3.x, fmaf(-py, q3.y, fmaf(-pz, q3.z, q3.w))));
    }
    float e = fminf(fminf(e0, e1), fminf(e2, e3));
    e = fminf(e, __shfl_xor(e, 1));
    e = fminf(e, __shfl_xor(e, 2));

    if (chunk == 0) {
        float pn = px * px + py * py + pz * pz;
        d0[(size_t)b * N + n] = 2.0f * e + pn;
    }
}

// Kernel B: per batch, bitonic-sort N floats in LDS, mean of smallest K, x2.
__global__ __launch_bounds__(1024, 1) void select_mean_kernel(
    const float* __restrict__ d0,
    float* __restrict__ out,
    int N, int Np2, int K)
{
    extern __shared__ float s[];
    const int b   = blockIdx.x;
    const int tid = threadIdx.x;

    for (int t = tid; t < Np2; t += 1024)
        s[t] = (t < N) ? d0[(size_t)b * N + t] : FLT_BIG;
    __syncthreads();

    for (int k = 2; k <= Np2; k <<= 1) {
        for (int j = k >> 1; j > 0; j >>= 1) {
            for (int t = tid; t < Np2; t += 1024) {
                int ixj = t ^ j;
                if (ixj > t) {
                    float a = s[t];
                    float c2 = s[ixj];
                    bool up = ((t & k) == 0);
                    if (up ? (a > c2) : (a < c2)) { s[t] = c2; s[ixj] = a; }
                }
            }
            __syncthreads();
        }
    }

    float sum = 0.0f;
    for (int t = tid; t < K; t += 1024) sum += s[t];
    __syncthreads();
    s[tid] = sum;
    __syncthreads();
    for (int off = 512; off > 0; off >>= 1) {
        if (tid < off) s[tid] += s[tid + off];
        __syncthreads();
    }
    if (tid == 0) out[b] = 2.0f * s[0] / (float)K;
}

extern "C" void kernel_launch(void* const* d_in, const int* in_sizes, int n_in,
                              void* d_out, int out_size, void* d_ws, size_t ws_size,
                              hipStream_t stream)
{
    const float* c   = (const float*)d_in[0];
    const float* dep = (const float*)d_in[1];
    const float* pc  = (const float*)d_in[2];
    float* out = (float*)d_out;

    const int B = in_sizes[0] / 25;
    const int N = in_sizes[1] / B;
    const int M = in_sizes[2] / (3 * B);
    int R = 1; while (R * R < N) R++;

    float* d0 = (float*)d_ws;   // B*N floats of scratch

    dim3 gridA(N / 64, B);
    size_t ldsA = (size_t)M * sizeof(float4);
    hipLaunchKernelGGL(chamfer_min_kernel, gridA, dim3(256), ldsA, stream,
                       c, dep, pc, d0, N, M, R);

    const int K = ((N < M) ? N : M) / 2;
    int Np2 = 1; while (Np2 < N) Np2 <<= 1;
    size_t ldsB = (size_t)Np2 * sizeof(float);
    hipLaunchKernelGGL(select_mean_kernel, dim3(B), dim3(1024), ldsB, stream,
                       d0, out, N, Np2, K);
}

// Round 3
// 91.290 us; speedup vs baseline: 1.5141x; 1.5141x over previous
//
#include <hip/hip_runtime.h>
#include <math.h>

#define FLT_BIG 3.0e38f

// Kernel A: per-ray min squared distance over M points.
// Block 256 = 8 ray-groups x 32 m-chunks. Each thread: 8 rays, M/32 points.
// LDS: M float4 (x,y,z, 0.5*|q|^2) = 64KB -> 2 blocks/CU.
// Per point per thread: 1 ds_read_b128 amortized over 8 rays (4 VALU/ray).
__global__ __launch_bounds__(256, 2) void chamfer_min_kernel(
    const float* __restrict__ cparam,   // B x 25
    const float* __restrict__ depth,    // B x N
    const float* __restrict__ pc,       // B x M x 3
    float* __restrict__ d0,             // B x N
    int N, int M, int R)
{
    const int b   = blockIdx.y;
    const int tid = threadIdx.x;

    extern __shared__ float4 s4[];      // M entries

    const float* pcb = pc + (size_t)b * M * 3;
    for (int idx = tid; idx < M; idx += 256) {
        float x = pcb[idx * 3 + 0];
        float y = pcb[idx * 3 + 1];
        float z = pcb[idx * 3 + 2];
        s4[idx] = make_float4(x, y, z, 0.5f * (x * x + y * y + z * z));
    }
    __syncthreads();

    const float* cb = cparam + (size_t)b * 25;
    const float fx = cb[16], sk = cb[17], cx = cb[18];
    const float fy = cb[20], cy = cb[21];

    const int chunk = tid & 31;              // m-chunk 0..31
    const int grp   = tid >> 5;              // ray group 0..7
    const int nbase = blockIdx.x * 64 + grp * 8;

    float px[8], py[8], pz[8], e[8];
    #pragma unroll
    for (int r = 0; r < 8; r++) {
        const int n = nbase + r;
        const int i = n / R;
        const int j = n - i * R;
        const float x_cam = (j + 0.5f) / (float)R;
        const float y_cam = (i + 0.5f) / (float)R;
        const float x_lift = (x_cam - cx + cy * sk / fy - sk * y_cam / fy) / fx;
        const float y_lift = (y_cam - cy) / fy;
        const float dxw = cb[0] * x_lift + cb[1] * y_lift + cb[2];
        const float dyw = cb[4] * x_lift + cb[5] * y_lift + cb[6];
        const float dzw = cb[8] * x_lift + cb[9] * y_lift + cb[10];
        const float inv = 1.0f / sqrtf(dxw * dxw + dyw * dyw + dzw * dzw);
        const float dep = depth[(size_t)b * N + n];
        px[r] = cb[3]  + dep * dxw * inv;
        py[r] = cb[7]  + dep * dyw * inv;
        pz[r] = cb[11] + dep * dzw * inv;
        e[r]  = FLT_BIG;
    }

    const int Mc = M >> 5;                   // points per chunk (128)
    #pragma unroll 4
    for (int m = 0; m < Mc; m++) {
        const float4 q = s4[(m << 5) + chunk];
        #pragma unroll
        for (int r = 0; r < 8; r++) {
            float t = fmaf(-px[r], q.x, q.w);
            t = fmaf(-py[r], q.y, t);
            t = fmaf(-pz[r], q.z, t);
            e[r] = fminf(e[r], t);
        }
    }

    // Reduce min across the 32 m-chunks (lanes 0..31 / 32..63 of the wave).
    #pragma unroll
    for (int r = 0; r < 8; r++) {
        float v = e[r];
        v = fminf(v, __shfl_xor(v, 1));
        v = fminf(v, __shfl_xor(v, 2));
        v = fminf(v, __shfl_xor(v, 4));
        v = fminf(v, __shfl_xor(v, 8));
        v = fminf(v, __shfl_xor(v, 16));
        e[r] = v;
    }
    if (chunk == 0) {
        #pragma unroll
        for (int r = 0; r < 8; r++) {
            const int n = nbase + r;
            const float pn = px[r] * px[r] + py[r] * py[r] + pz[r] * pz[r];
            d0[(size_t)b * N + n] = 2.0f * e[r] + pn;
        }
    }
}

// Kernel B: exact sum of the K smallest of N values via 4-round radix select
// on order-preserving transformed float bits. One block (256 thr) per batch.
__global__ __launch_bounds__(256, 1) void select_mean_kernel(
    const float* __restrict__ d0,
    float* __restrict__ out,
    int N, int K)
{
    const int b   = blockIdx.x;
    const int tid = threadIdx.x;

    extern __shared__ unsigned int sm[];
    unsigned int* keys = sm;              // N
    unsigned int* hist = sm + N;          // 256
    unsigned int* cum  = sm + N + 256;    // 256
    __shared__ unsigned int sel_digit, sel_k;
    __shared__ float  partial[4];
    __shared__ unsigned int pcnt[4];

    // Load + order-preserving transform (handles tiny negatives from rounding).
    for (int t = tid; t < N; t += 256) {
        unsigned int bts = __float_as_uint(d0[(size_t)b * N + t]);
        keys[t] = (bts & 0x80000000u) ? ~bts : (bts | 0x80000000u);
    }
    if (tid == 0) sel_k = (unsigned int)K;
    __syncthreads();

    unsigned int prefix = 0u, mask = 0u;
    for (int round = 0; round < 4; round++) {
        const int shift = 24 - 8 * round;
        hist[tid] = 0u;
        __syncthreads();

        for (int t = tid; t < N; t += 256) {
            unsigned int kk = keys[t];
            if ((kk & mask) == prefix)
                atomicAdd(&hist[(kk >> shift) & 255u], 1u);
        }
        __syncthreads();

        // Inclusive prefix sum of 256 bins by wave 0 (4 chunks of 64).
        if (tid < 64) {
            unsigned int carry = 0u;
            for (int c = 0; c < 4; c++) {
                unsigned int v = hist[c * 64 + tid];
                #pragma unroll
                for (int off = 1; off < 64; off <<= 1) {
                    unsigned int nb = __shfl_up(v, off);
                    if (tid >= off) v += nb;
                }
                cum[c * 64 + tid] = v + carry;
                carry += __shfl(v, 63);
            }
        }
        __syncthreads();

        const unsigned int k = sel_k;
        __syncthreads();                   // everyone reads k before the winner writes
        const unsigned int cthis = cum[tid];
        const unsigned int cprev = (tid == 0) ? 0u : cum[tid - 1];
        if (cprev < k && k <= cthis) {
            sel_digit = (unsigned int)tid;
            sel_k     = k - cprev;
        }
        __syncthreads();

        prefix |= (sel_digit << shift);
        mask   |= (255u << shift);
    }
    // prefix == transformed key of the K-th smallest value (T).

    float sum = 0.0f;
    unsigned int cnt = 0u;
    for (int t = tid; t < N; t += 256) {
        unsigned int kk = keys[t];
        if (kk < prefix) {
            unsigned int bts = (kk & 0x80000000u) ? (kk & 0x7fffffffu) : ~kk;
            sum += __uint_as_float(bts);
            cnt++;
        }
    }
    #pragma unroll
    for (int off = 32; off > 0; off >>= 1) {
        sum += __shfl_xor(sum, off);
        cnt += __shfl_xor(cnt, off);
    }
    const int lane = tid & 63;
    const int wv   = tid >> 6;
    if (lane == 0) { partial[wv] = sum; pcnt[wv] = cnt; }
    __syncthreads();
    if (tid == 0) {
        float s = partial[0] + partial[1] + partial[2] + partial[3];
        unsigned int c = pcnt[0] + pcnt[1] + pcnt[2] + pcnt[3];
        unsigned int bts = (prefix & 0x80000000u) ? (prefix & 0x7fffffffu) : ~prefix;
        float tval = __uint_as_float(bts);
        s += (float)(K - (int)c) * tval;
        out[b] = 2.0f * s / (float)K;
    }
}

extern "C" void kernel_launch(void* const* d_in, const int* in_sizes, int n_in,
                              void* d_out, int out_size, void* d_ws, size_t ws_size,
                              hipStream_t stream)
{
    const float* c   = (const float*)d_in[0];
    const float* dep = (const float*)d_in[1];
    const float* pc  = (const float*)d_in[2];
    float* out = (float*)d_out;

    const int B = in_sizes[0] / 25;
    const int N = in_sizes[1] / B;
    const int M = in_sizes[2] / (3 * B);
    int R = 1; while (R * R < N) R++;

    float* d0 = (float*)d_ws;   // B*N floats of scratch

    dim3 gridA(N / 64, B);
    size_t ldsA = (size_t)M * sizeof(float4);
    hipLaunchKernelGGL(chamfer_min_kernel, gridA, dim3(256), ldsA, stream,
                       c, dep, pc, d0, N, M, R);

    const int K = ((N < M) ? N : M) / 2;
    size_t ldsB = (size_t)(N + 512) * sizeof(unsigned int);
    hipLaunchKernelGGL(select_mean_kernel, dim3(B), dim3(256), ldsB, stream,
                       d0, out, N, K);
}